// Round 8
// baseline (1357.803 us; speedup 1.0000x reference)
//
#include <hip/hip_runtime.h>
#include <math.h>

namespace {
constexpr int LSEQ = 32;
constexpr int CDIM = 64;
constexpr int HDIM = 128;
constexpr int FDIM = 32;
constexpr float TWO_PI = 6.28318530717958647692f;

__device__ __forceinline__ float sigf(float x) { return 1.0f / (1.0f + __expf(-x)); }
__device__ __forceinline__ float tanh_fast(float x) { return 1.0f - 2.0f / (__expf(2.0f * x) + 1.0f); }
}

// S=2 sequences/block, 512 blocks (2/CU!), 512 threads (8 waves).
// Two independent blocks per CU: no shared barriers, so one block's waves
// execute while the other drains its __syncthreads -> latency hiding without
// the 1024-thread 64-VGPR compiler cliff (R4/R6 post-mortems).
// LDS ~74.4 KB <= 80 KB so 2 blocks fit; launch_bounds(512,2) caps VGPR at 128.
__global__ __launch_bounds__(512, 2)
void sfm_lstm_r8(const float* __restrict__ x,
                 const float* __restrict__ Q, const float* __restrict__ R,
                 const float* __restrict__ Wi, const float* __restrict__ bi,
                 const float* __restrict__ Wg, const float* __restrict__ bg,
                 const float* __restrict__ Wste, const float* __restrict__ bste,
                 const float* __restrict__ Wfre, const float* __restrict__ bfre,
                 const float* __restrict__ Wom, const float* __restrict__ bom,
                 const float* __restrict__ Wo, const float* __restrict__ bo,
                 const float* __restrict__ Wa, const float* __restrict__ ba,
                 const float* __restrict__ Wout, const float* __restrict__ bout,
                 float* __restrict__ out)
{
    const int t = threadIdx.x;
    const int blk = blockIdx.x;

    __shared__ float sQ[HDIM * CDIM];                  // Q[k][c]   32 KB
    __shared__ float sR[CDIM * HDIM];                  // R[k][j]   32 KB
    // soh[320][2]: rows 0..63 = xt, 64..191 = h, 192..319 = c_t  ([dim][seq])
    __shared__ __align__(8) float soh[320][2];
    __shared__ __align__(8) float sit[HDIM][2];
    __shared__ __align__(8) float schat[HDIM][2];
    __shared__ __align__(8) float sfste[HDIM][2];
    __shared__ __align__(8) float sffre[FDIM][2];
    __shared__ __align__(8) float scosv[FDIM][2];
    __shared__ __align__(8) float ssinv[FDIM][2];
    __shared__ __align__(8) float spart[1024];         // 4 KB partials
    __shared__ float swa[FDIM];

    #pragma unroll
    for (int i = 0; i < 16; ++i) sQ[t + 512 * i] = Q[t + 512 * i];
    #pragma unroll
    for (int i = 0; i < 16; ++i) sR[t + 512 * i] = R[t + 512 * i];
    if (t < FDIM) swa[t] = Wa[t];
    if (t < 256) soh[64 + (t >> 1)][t & 1] = 0.0f;     // h = 0

    // per-thread complex state: (row, seq, f-half) -> 128*2*2 = 512 = blockDim
    const int srow = t >> 2, sseq = (t >> 1) & 1, shalf = t & 1;
    const int f0 = shalf * (FDIM / 2);
    float re[FDIM / 2], im[FDIM / 2];
    #pragma unroll
    for (int j = 0; j < FDIM / 2; ++j) { re[j] = 0.0f; im[j] = 0.0f; }

    // gate role: threads 0..447 own one output col of the concatenated gates
    const float* wG = nullptr; const float* bG = nullptr;
    int strG = HDIM, gcol = 0, reg = -1;
    if      (t < 128) { wG = Wi;   bG = bi;   strG = HDIM; gcol = t;       reg = 0; }
    else if (t < 256) { wG = Wg;   bG = bg;   strG = HDIM; gcol = t - 128; reg = 1; }
    else if (t < 384) { wG = Wste; bG = bste; strG = HDIM; gcol = t - 256; reg = 2; }
    else if (t < 416) { wG = Wfre; bG = bfre; strG = FDIM; gcol = t - 384; reg = 3; }
    else if (t < 448) { wG = Wom;  bG = bom;  strG = FDIM; gcol = t - 416; reg = 4; }
    const float gb = (reg >= 0) ? bG[gcol] : 0.0f;
    const float* wGp0 = (reg >= 0) ? (wG + gcol) : Wi;

    const float ba0 = ba[0];
    const float bo_r = bo[t >> 1];                     // out-reduce col (t<256)
    const float* xbase = x + (size_t)blk * 2 * LSEQ * CDIM;

    const int ocol = t & 127, oks = t >> 7;            // out: 128 cols x 4 k-slices of 80
    const float* woP = Wo + ocol;
    const int pl = t - 448;                            // prefetch lane (wave 7)

    // prologue: load x(ts=0): 128 values (64 cols x 2 seqs)
    if (t < 128) soh[t & 63][t >> 6] = xbase[((t >> 6) * LSEQ) * CDIM + (t & 63)];
    __syncthreads();

    for (int ts = 0; ts < LSEQ; ++ts) {
        // ---- mogrify x,h,x,h,x ----
        #pragma unroll
        for (int m = 0; m < 5; ++m) {
            if ((m & 1) == 0) {
                // xt = 2*sig(h @ Q) * xt : 64 cols x 8 k-slices of 16
                const int c = t & 63, k0 = (t >> 6) * 16;
                float a0 = 0.f, a1 = 0.f;
                #pragma unroll
                for (int kk = 0; kk < 16; ++kk) {
                    const int k = k0 + kk;
                    const float qv = sQ[k * CDIM + c];
                    const float2 h2 = *(const float2*)&soh[64 + k][0];
                    a0 += qv * h2.x; a1 += qv * h2.y;
                }
                *(float2*)&spart[(t >> 6) * 128 + c * 2] = make_float2(a0, a1);
                __syncthreads();
                if (t < 128) {
                    float v = 0.f;
                    #pragma unroll
                    for (int i = 0; i < 8; ++i) v += spart[i * 128 + t];
                    soh[t >> 1][t & 1] = 2.0f * sigf(v) * soh[t >> 1][t & 1];
                }
                __syncthreads();
            } else {
                // h = 2*sig(x @ R) * h : 128 cols x 4 k-slices of 16
                const int j = t & 127, k0 = (t >> 7) * 16;
                float a0 = 0.f, a1 = 0.f;
                #pragma unroll
                for (int kk = 0; kk < 16; ++kk) {
                    const int k = k0 + kk;
                    const float rv = sR[k * HDIM + j];
                    const float2 x2 = *(const float2*)&soh[k][0];
                    a0 += rv * x2.x; a1 += rv * x2.y;
                }
                *(float2*)&spart[(t >> 7) * 256 + j * 2] = make_float2(a0, a1);
                __syncthreads();
                if (t < 256) {
                    float v = spart[t] + spart[256 + t] + spart[512 + t] + spart[768 + t];
                    soh[64 + (t >> 1)][t & 1] = 2.0f * sigf(v) * soh[64 + (t >> 1)][t & 1];
                }
                __syncthreads();
            }
        }

        // ---- gates (threads 0-447) + x prefetch (wave 7) ----
        float xn0 = 0.f, xn1 = 0.f;
        if (reg >= 0) {
            float g0 = 0.f, g1 = 0.f;
            const float* wp = wGp0;
            #pragma unroll 8
            for (int k = 0; k < CDIM + HDIM; ++k) {
                const float w = *wp; wp += strG;
                const float2 i2 = *(const float2*)&soh[k][0];
                g0 += w * i2.x; g1 += w * i2.y;
            }
            g0 += gb; g1 += gb;
            if (reg == 4) {
                const float o0 = TWO_PI * sigf(g0), o1 = TWO_PI * sigf(g1);
                *(float2*)&scosv[gcol][0] = make_float2(__cosf(o0), __cosf(o1));
                *(float2*)&ssinv[gcol][0] = make_float2(__sinf(o0), __sinf(o1));
            } else {
                float* d = (reg == 0) ? &sit[0][0] : (reg == 1) ? &schat[0][0]
                         : (reg == 2) ? &sfste[0][0] : &sffre[0][0];
                *(float2*)&d[gcol * 2] = make_float2(sigf(g0), sigf(g1));
            }
        } else if (ts + 1 < LSEQ) {
            xn0 = xbase[(ts + 1) * CDIM + pl];
            xn1 = xbase[(LSEQ + ts + 1) * CDIM + pl];
        }
        __syncthreads();

        // ---- complex state update + amplitude @ Wa -> c_t : (row,seq,f-half)/thread ----
        {
            const float ic = sit[srow][sseq] * schat[srow][sseq];
            const float fs = sfste[srow][sseq];
            float acc = 0.f;
            #pragma unroll
            for (int j = 0; j < FDIM / 2; ++j) {
                const int f = f0 + j;
                const float ft = fs * sffre[f][sseq];
                const float cv = scosv[f][sseq], sv = ssinv[f][sseq];
                re[j] = ft * re[j] + ic * cv;
                im[j] = ft * im[j] + ic * sv;
                acc += sqrtf(re[j] * re[j] + im[j] * im[j]) * swa[f];
            }
            acc += __shfl_xor(acc, 1);
            if (shalf == 0) soh[192 + srow][sseq] = tanh_fast(acc + ba0);
        }
        __syncthreads();

        // ---- o_t partial: oh(320) @ Wo, 128 cols x 4 k-slices of 80 ----
        {
            float o0 = 0.f, o1 = 0.f;
            const int k0 = oks * 80;
            const float* wp = woP + k0 * HDIM;
            #pragma unroll 8
            for (int kk = 0; kk < 80; ++kk) {
                const float w = *wp; wp += HDIM;
                const float2 i2 = *(const float2*)&soh[k0 + kk][0];
                o0 += w * i2.x; o1 += w * i2.y;
            }
            *(float2*)&spart[oks * 256 + ocol * 2] = make_float2(o0, o1);
        }
        __syncthreads();

        // ---- out reduce -> h update; wave 7 commits prefetched x ----
        if (t < 256) {
            const float v = spart[t] + spart[256 + t] + spart[512 + t] + spart[768 + t];
            const float o = sigf(v + bo_r);
            soh[64 + (t >> 1)][t & 1] = o * tanh_fast(soh[192 + (t >> 1)][t & 1]);
        } else if (t >= 448 && ts + 1 < LSEQ) {
            soh[pl][0] = xn0; soh[pl][1] = xn1;
        }
        __syncthreads();
    }

    // ---- out = h_last @ Wout + bout, one wave per sequence ----
    if (t < 128) {
        const int w = t >> 6, l = t & 63;
        float p = soh[64 + l][w] * Wout[l] + soh[128 + l][w] * Wout[64 + l];
        #pragma unroll
        for (int off = 32; off > 0; off >>= 1) p += __shfl_xor(p, off);
        if (l == 0) out[blk * 2 + w] = p + bout[0];
    }
}

extern "C" void kernel_launch(void* const* d_in, const int* in_sizes, int n_in,
                              void* d_out, int out_size, void* d_ws, size_t ws_size,
                              hipStream_t stream) {
    const float* x    = (const float*)d_in[0];
    const float* Q    = (const float*)d_in[1];
    const float* R    = (const float*)d_in[2];
    const float* Wi   = (const float*)d_in[3];
    const float* bi   = (const float*)d_in[4];
    const float* Wg   = (const float*)d_in[5];
    const float* bg   = (const float*)d_in[6];
    const float* Wste = (const float*)d_in[7];
    const float* bste = (const float*)d_in[8];
    const float* Wfre = (const float*)d_in[9];
    const float* bfre = (const float*)d_in[10];
    const float* Wom  = (const float*)d_in[11];
    const float* bom  = (const float*)d_in[12];
    const float* Wo   = (const float*)d_in[13];
    const float* bo   = (const float*)d_in[14];
    const float* Wa   = (const float*)d_in[15];
    const float* ba   = (const float*)d_in[16];
    const float* Wout = (const float*)d_in[17];
    const float* bout = (const float*)d_in[18];
    float* out = (float*)d_out;

    sfm_lstm_r8<<<dim3(512), dim3(512), 0, stream>>>(
        x, Q, R, Wi, bi, Wg, bg, Wste, bste, Wfre, bfre, Wom, bom,
        Wo, bo, Wa, ba, Wout, bout, out);
}

// Round 9
// 384.589 us; speedup vs baseline: 3.5305x; 3.5305x over previous
//
#include <hip/hip_runtime.h>
#include <math.h>

namespace {
constexpr int LSEQ = 32;
constexpr int CDIM = 64;
constexpr int HDIM = 128;
constexpr int FDIM = 32;
constexpr float TWO_PI = 6.28318530717958647692f;

__device__ __forceinline__ float sigf(float x) { return 1.0f / (1.0f + __expf(-x)); }
__device__ __forceinline__ float tanh_fast(float x) { return 1.0f - 2.0f / (__expf(2.0f * x) + 1.0f); }
}

// S=4 seqs/block, 256 blocks (1/CU), 512 threads (8 waves). R3 frame with
// float4 weight streams: gates = 4 cols/thread x 4 k-slices (48 float4 loads),
// out = 4 cols/thread x 16 k-slices (20 float4 loads), x(ts+1) prefetched by
// the gate-idle wave. Mogrify/state phases are R3-verbatim (proven layouts).
__global__ __launch_bounds__(512, 1)
void sfm_lstm_r9(const float* __restrict__ x,
                 const float* __restrict__ Q, const float* __restrict__ R,
                 const float* __restrict__ Wi, const float* __restrict__ bi,
                 const float* __restrict__ Wg, const float* __restrict__ bg,
                 const float* __restrict__ Wste, const float* __restrict__ bste,
                 const float* __restrict__ Wfre, const float* __restrict__ bfre,
                 const float* __restrict__ Wom, const float* __restrict__ bom,
                 const float* __restrict__ Wo, const float* __restrict__ bo,
                 const float* __restrict__ Wa, const float* __restrict__ ba,
                 const float* __restrict__ Wout, const float* __restrict__ bout,
                 float* __restrict__ out)
{
    const int t = threadIdx.x;
    const int blk = blockIdx.x;

    __shared__ float sQ[HDIM * CDIM];                  // Q[k][c]  32 KB
    __shared__ float sR[CDIM * HDIM];                  // R[k][j]  32 KB
    // soh[320][4]: rows 0..63 = xt, 64..191 = h, 192..319 = c_t  ([dim][seq])
    __shared__ __align__(16) float soh[320][4];
    __shared__ __align__(16) float sit[HDIM][4];
    __shared__ __align__(16) float schat[HDIM][4];
    __shared__ __align__(16) float sfste[HDIM][4];
    __shared__ __align__(16) float sffre[FDIM][4];
    __shared__ __align__(16) float scosv[FDIM][4];
    __shared__ __align__(16) float ssinv[FDIM][4];
    __shared__ __align__(16) float spart[8192];        // 32 KB shared partials
    __shared__ float swa[FDIM];

    #pragma unroll
    for (int i = 0; i < 16; ++i) sQ[t + 512 * i] = Q[t + 512 * i];
    #pragma unroll
    for (int i = 0; i < 16; ++i) sR[t + 512 * i] = R[t + 512 * i];
    if (t < FDIM) swa[t] = Wa[t];
    soh[64 + (t >> 2)][t & 3] = 0.0f;                  // h = 0 (512 = 128x4)

    // state role: (row r7, seq sA), full F per thread
    const int r7 = t & 127, sA = t >> 7;
    float re[FDIM], im[FDIM];
    #pragma unroll
    for (int f = 0; f < FDIM; ++f) { re[f] = 0.0f; im[f] = 0.0f; }

    // ---- gate PARTIAL role (t<448): group gg owns cols 4gg..4gg+3, k-slice gks
    const int gks = t / 112, gg = t - gks * 112;
    const int gcol0 = 4 * gg;
    const float* wPt = Wi; int strP = HDIM;
    if      (gcol0 < 128) { wPt = Wi   + gcol0;         strP = HDIM; }
    else if (gcol0 < 256) { wPt = Wg   + (gcol0 - 128); strP = HDIM; }
    else if (gcol0 < 384) { wPt = Wste + (gcol0 - 256); strP = HDIM; }
    else if (gcol0 < 416) { wPt = Wfre + (gcol0 - 384); strP = FDIM; }
    else                  { wPt = Wom  + (gcol0 - 416); strP = FDIM; }
    wPt += (size_t)(48 * gks) * strP;

    // ---- gate REDUCE role (t<448): col = t
    const float* bG = bi; int reg = -1, gcol = 0;
    if      (t < 128) { bG = bi;   gcol = t;       reg = 0; }
    else if (t < 256) { bG = bg;   gcol = t - 128; reg = 1; }
    else if (t < 384) { bG = bste; gcol = t - 256; reg = 2; }
    else if (t < 416) { bG = bfre; gcol = t - 384; reg = 3; }
    else if (t < 448) { bG = bom;  gcol = t - 416; reg = 4; }
    const float gb = (reg >= 0) ? bG[gcol] : 0.0f;

    // ---- out roles
    const int oks = t >> 5, og = t & 31;               // 16 k-slices x 32 col-groups
    const float* woPt = Wo + 4 * og + (size_t)(20 * oks) * HDIM;
    const float bo_r = (t < 128) ? bo[t] : 0.0f;

    const float ba0 = ba[0];
    const float* xbase = x + (size_t)blk * 4 * LSEQ * CDIM;
    const int pl = t - 448;                            // prefetch lane (wave 7)

    // prologue: x(ts=0)
    if (t < 256) soh[t & 63][t >> 6] = xbase[((t >> 6) * LSEQ) * CDIM + (t & 63)];
    __syncthreads();

    for (int ts = 0; ts < LSEQ; ++ts) {
        // ---- mogrify x,h,x,h,x (R3-verbatim) ----
        #pragma unroll
        for (int m = 0; m < 5; ++m) {
            if ((m & 1) == 0) {
                const int c = t & 63, k0 = (t >> 6) * 16;
                float a0 = 0.f, a1 = 0.f, a2 = 0.f, a3 = 0.f;
                #pragma unroll
                for (int kk = 0; kk < 16; ++kk) {
                    const int k = k0 + kk;
                    const float qv = sQ[k * CDIM + c];
                    const float4 h4 = *(const float4*)&soh[64 + k][0];
                    a0 += qv * h4.x; a1 += qv * h4.y; a2 += qv * h4.z; a3 += qv * h4.w;
                }
                *(float4*)&spart[(t >> 6) * 256 + c * 4] = make_float4(a0, a1, a2, a3);
                __syncthreads();
                if (t < 256) {
                    float v = 0.f;
                    #pragma unroll
                    for (int i = 0; i < 8; ++i) v += spart[i * 256 + t];
                    soh[t >> 2][t & 3] = 2.0f * sigf(v) * soh[t >> 2][t & 3];
                }
                __syncthreads();
            } else {
                const int j = t & 127, k0 = (t >> 7) * 16;
                float a0 = 0.f, a1 = 0.f, a2 = 0.f, a3 = 0.f;
                #pragma unroll
                for (int kk = 0; kk < 16; ++kk) {
                    const int k = k0 + kk;
                    const float rv = sR[k * HDIM + j];
                    const float4 x4 = *(const float4*)&soh[k][0];
                    a0 += rv * x4.x; a1 += rv * x4.y; a2 += rv * x4.z; a3 += rv * x4.w;
                }
                *(float4*)&spart[(t >> 7) * 512 + j * 4] = make_float4(a0, a1, a2, a3);
                __syncthreads();
                {
                    const float v = spart[t] + spart[512 + t] + spart[1024 + t] + spart[1536 + t];
                    soh[64 + (t >> 2)][t & 3] = 2.0f * sigf(v) * soh[64 + (t >> 2)][t & 3];
                }
                __syncthreads();
            }
        }

        // ---- gate partials (t<448): 48 float4 weight loads, 16 FMA each ----
        float xn0 = 0.f, xn1 = 0.f, xn2 = 0.f, xn3 = 0.f;
        if (t < 448) {
            float a00 = 0.f, a01 = 0.f, a02 = 0.f, a03 = 0.f;
            float a10 = 0.f, a11 = 0.f, a12 = 0.f, a13 = 0.f;
            float a20 = 0.f, a21 = 0.f, a22 = 0.f, a23 = 0.f;
            float a30 = 0.f, a31 = 0.f, a32 = 0.f, a33 = 0.f;
            const float* wp = wPt;
            const int kb = 48 * gks;
            #pragma unroll 8
            for (int kk = 0; kk < 48; ++kk) {
                const float4 w4 = *(const float4*)wp; wp += strP;
                const float4 i4 = *(const float4*)&soh[kb + kk][0];
                a00 += w4.x * i4.x; a01 += w4.x * i4.y; a02 += w4.x * i4.z; a03 += w4.x * i4.w;
                a10 += w4.y * i4.x; a11 += w4.y * i4.y; a12 += w4.y * i4.z; a13 += w4.y * i4.w;
                a20 += w4.z * i4.x; a21 += w4.z * i4.y; a22 += w4.z * i4.z; a23 += w4.z * i4.w;
                a30 += w4.w * i4.x; a31 += w4.w * i4.y; a32 += w4.w * i4.z; a33 += w4.w * i4.w;
            }
            float* sp = &spart[(gks * 448 + gcol0) * 4];
            *(float4*)(sp)      = make_float4(a00, a01, a02, a03);
            *(float4*)(sp + 4)  = make_float4(a10, a11, a12, a13);
            *(float4*)(sp + 8)  = make_float4(a20, a21, a22, a23);
            *(float4*)(sp + 12) = make_float4(a30, a31, a32, a33);
        } else if (ts + 1 < LSEQ) {
            xn0 = xbase[(0 * LSEQ + ts + 1) * CDIM + pl];
            xn1 = xbase[(1 * LSEQ + ts + 1) * CDIM + pl];
            xn2 = xbase[(2 * LSEQ + ts + 1) * CDIM + pl];
            xn3 = xbase[(3 * LSEQ + ts + 1) * CDIM + pl];
        }
        __syncthreads();

        // ---- gate reduce (t<448): col t, 4 seqs ----
        if (reg >= 0) {
            float4 v = make_float4(0.f, 0.f, 0.f, 0.f);
            #pragma unroll
            for (int ks = 0; ks < 4; ++ks) {
                const float4 p4 = *(const float4*)&spart[(ks * 448 + t) * 4];
                v.x += p4.x; v.y += p4.y; v.z += p4.z; v.w += p4.w;
            }
            v.x += gb; v.y += gb; v.z += gb; v.w += gb;
            if (reg == 4) {
                const float o0 = TWO_PI * sigf(v.x), o1 = TWO_PI * sigf(v.y);
                const float o2 = TWO_PI * sigf(v.z), o3 = TWO_PI * sigf(v.w);
                *(float4*)&scosv[gcol][0] = make_float4(__cosf(o0), __cosf(o1), __cosf(o2), __cosf(o3));
                *(float4*)&ssinv[gcol][0] = make_float4(__sinf(o0), __sinf(o1), __sinf(o2), __sinf(o3));
            } else {
                float* d = (reg == 0) ? &sit[0][0] : (reg == 1) ? &schat[0][0]
                         : (reg == 2) ? &sfste[0][0] : &sffre[0][0];
                *(float4*)&d[gcol * 4] = make_float4(sigf(v.x), sigf(v.y), sigf(v.z), sigf(v.w));
            }
        }
        __syncthreads();

        // ---- complex state + amplitude @ Wa -> c_t (R3-verbatim, col-major arrays) ----
        {
            const float ic = sit[r7][sA] * schat[r7][sA];
            const float fs = sfste[r7][sA];
            float acc = 0.f;
            #pragma unroll
            for (int f = 0; f < FDIM; ++f) {
                const float ft = fs * sffre[f][sA];
                const float cv = scosv[f][sA], sv = ssinv[f][sA];
                re[f] = ft * re[f] + ic * cv;
                im[f] = ft * im[f] + ic * sv;
                acc += sqrtf(re[f] * re[f] + im[f] * im[f]) * swa[f];
            }
            soh[192 + r7][sA] = tanh_fast(acc + ba0);
        }
        __syncthreads();

        // ---- out partials: all 512, 20 float4 loads, 16 FMA each ----
        {
            float a00 = 0.f, a01 = 0.f, a02 = 0.f, a03 = 0.f;
            float a10 = 0.f, a11 = 0.f, a12 = 0.f, a13 = 0.f;
            float a20 = 0.f, a21 = 0.f, a22 = 0.f, a23 = 0.f;
            float a30 = 0.f, a31 = 0.f, a32 = 0.f, a33 = 0.f;
            const float* wp = woPt;
            const int kb = 20 * oks;
            #pragma unroll 5
            for (int kk = 0; kk < 20; ++kk) {
                const float4 w4 = *(const float4*)wp; wp += HDIM;
                const float4 i4 = *(const float4*)&soh[kb + kk][0];
                a00 += w4.x * i4.x; a01 += w4.x * i4.y; a02 += w4.x * i4.z; a03 += w4.x * i4.w;
                a10 += w4.y * i4.x; a11 += w4.y * i4.y; a12 += w4.y * i4.z; a13 += w4.y * i4.w;
                a20 += w4.z * i4.x; a21 += w4.z * i4.y; a22 += w4.z * i4.z; a23 += w4.z * i4.w;
                a30 += w4.w * i4.x; a31 += w4.w * i4.y; a32 += w4.w * i4.z; a33 += w4.w * i4.w;
            }
            float* sp = &spart[(oks * 128 + 4 * og) * 4];
            *(float4*)(sp)      = make_float4(a00, a01, a02, a03);
            *(float4*)(sp + 4)  = make_float4(a10, a11, a12, a13);
            *(float4*)(sp + 8)  = make_float4(a20, a21, a22, a23);
            *(float4*)(sp + 12) = make_float4(a30, a31, a32, a33);
        }
        __syncthreads();

        // ---- out reduce (t<128, float4 over seqs) + x commit (wave 7) ----
        if (t < 128) {
            float4 v = make_float4(0.f, 0.f, 0.f, 0.f);
            #pragma unroll
            for (int ks = 0; ks < 16; ++ks) {
                const float4 p4 = *(const float4*)&spart[(ks * 128 + t) * 4];
                v.x += p4.x; v.y += p4.y; v.z += p4.z; v.w += p4.w;
            }
            const float4 ct4 = *(const float4*)&soh[192 + t][0];
            float4 h4;
            h4.x = sigf(v.x + bo_r) * tanh_fast(ct4.x);
            h4.y = sigf(v.y + bo_r) * tanh_fast(ct4.y);
            h4.z = sigf(v.z + bo_r) * tanh_fast(ct4.z);
            h4.w = sigf(v.w + bo_r) * tanh_fast(ct4.w);
            *(float4*)&soh[64 + t][0] = h4;
        } else if (t >= 448 && ts + 1 < LSEQ) {
            soh[pl][0] = xn0; soh[pl][1] = xn1;
            soh[pl][2] = xn2; soh[pl][3] = xn3;
        }
        __syncthreads();
    }

    // ---- out = h_last @ Wout + bout, one wave per sequence ----
    if (t < 256) {
        const int w = t >> 6, l = t & 63;
        float p = soh[64 + l][w] * Wout[l] + soh[128 + l][w] * Wout[64 + l];
        #pragma unroll
        for (int off = 32; off > 0; off >>= 1) p += __shfl_xor(p, off);
        if (l == 0) out[blk * 4 + w] = p + bout[0];
    }
}

extern "C" void kernel_launch(void* const* d_in, const int* in_sizes, int n_in,
                              void* d_out, int out_size, void* d_ws, size_t ws_size,
                              hipStream_t stream) {
    const float* x    = (const float*)d_in[0];
    const float* Q    = (const float*)d_in[1];
    const float* R    = (const float*)d_in[2];
    const float* Wi   = (const float*)d_in[3];
    const float* bi   = (const float*)d_in[4];
    const float* Wg   = (const float*)d_in[5];
    const float* bg   = (const float*)d_in[6];
    const float* Wste = (const float*)d_in[7];
    const float* bste = (const float*)d_in[8];
    const float* Wfre = (const float*)d_in[9];
    const float* bfre = (const float*)d_in[10];
    const float* Wom  = (const float*)d_in[11];
    const float* bom  = (const float*)d_in[12];
    const float* Wo   = (const float*)d_in[13];
    const float* bo   = (const float*)d_in[14];
    const float* Wa   = (const float*)d_in[15];
    const float* ba   = (const float*)d_in[16];
    const float* Wout = (const float*)d_in[17];
    const float* bout = (const float*)d_in[18];
    float* out = (float*)d_out;

    sfm_lstm_r9<<<dim3(256), dim3(512), 0, stream>>>(
        x, Q, R, Wi, bi, Wg, bg, Wste, bste, Wfre, bfre, Wom, bom,
        Wo, bo, Wa, ba, Wout, bout, out);
}